// Round 7
// baseline (195.395 us; speedup 1.0000x reference)
//
#include <hip/hip_runtime.h>
#include <math.h>

// S4D via chunked linear-scan recurrence. x (L,B,D) f32, out (L,B,D) f32.
// Round 7: packed-f32 state math (v_pk_fma_f32) — 2 states per ext_vector.
#define L_SEQ  4096
#define BSZ    4
#define DM     1024
#define NS     16
#define NSH    8                  // states per thread (n-split across wave halves)
#define NV     (NSH / 2)          // v2f vectors per array (2 states each)
#define NCHUNK 64
#define CHUNK  (L_SEQ / NCHUNK)   // 64
#define LOG2_CHUNK 6
#define SCALE  0.25f
#define LBD    (BSZ * DM)         // 4096, x stride per l

typedef float v2f __attribute__((ext_vector_type(2)));

// ws layout:
//   qbuf float2[NS*DM]            128 KiB   (indexed n*DM + d)
//   pbuf float2[NS*DM]            128 KiB
//   S    float2[BSZ*NCHUNK*NS*DM] 33.5 MiB  (indexed ((bc*NS)+n)*DM + d)

// ---------------------------------------------------------------- params
__global__ void s4d_params(const float* __restrict__ log_dt,
                           const float* __restrict__ log_A_real,
                           const float* __restrict__ A_imag,
                           const float* __restrict__ Bp,
                           const float* __restrict__ Cp,
                           float2* __restrict__ qbuf,
                           float2* __restrict__ pbuf) {
    int t = blockIdx.x * blockDim.x + threadIdx.x;   // t = n*DM + d
    if (t >= NS * DM) return;
    int n = t >> 10, d = t & (DM - 1);
    int i = d * NS + n;                              // input layout (D,N)
    float dt = expf(log_dt[d]);
    float Ar = -expf(log_A_real[i]);
    float Ai = A_imag[i];
    float ar = 0.5f * Ar * dt, ai = 0.5f * Ai * dt;  // dtA/2
    float den_r = 1.0f - ar, den_i = -ai;            // 1 - dtA/2
    float num_r = 1.0f + ar, num_i = ai;             // 1 + dtA/2
    float inv = 1.0f / (den_r * den_r + den_i * den_i);
    float qr = (num_r * den_r + num_i * den_i) * inv;
    float qi = (num_i * den_r - num_r * den_i) * inv;
    float B0 = Bp[2 * i], B1 = Bp[2 * i + 1];
    float C0 = Cp[2 * i], C1 = Cp[2 * i + 1];
    float ccr = B0 * C0 - B1 * C1;
    float cci = B0 * C1 + B1 * C0;
    float s = dt * inv * SCALE;
    float pr = (ccr * den_r + cci * den_i) * s;
    float pi = (cci * den_r - ccr * den_i) * s;
    qbuf[t] = make_float2(qr, qi);
    pbuf[t] = make_float2(pr, pi);
}

// ---------------------------------------------------------------- pass 1
// 2 threads per (b,c,d), 8 states each (4 v2f pairs), from h=0.
__attribute__((amdgpu_waves_per_eu(4, 4)))
__global__ __launch_bounds__(256)
void s4d_pass1(const float* __restrict__ x,
               const float2* __restrict__ qbuf,
               float2* __restrict__ S) {
    int tid  = blockIdx.x * 256 + threadIdx.x;       // 2*BSZ*NCHUNK*DM threads
    int lane = tid & 63;
    int dlo  = lane & 31;
    int half = lane >> 5;
    int u    = tid >> 6;
    int dhi  = u & 31;
    int bc   = u >> 5;                               // b*NCHUNK + c
    int c    = bc & (NCHUNK - 1);
    int d    = dhi * 32 + dlo;
    int b    = bc >> LOG2_CHUNK;
    int nb   = half * NSH;

    v2f Qr[NV], Qi[NV], Hr[NV], Hi[NV];
#pragma unroll
    for (int k = 0; k < NV; ++k) {
        float2 a = qbuf[(nb + 2 * k) * DM + d];
        float2 bq = qbuf[(nb + 2 * k + 1) * DM + d];
        Qr[k] = (v2f){a.x, bq.x};
        Qi[k] = (v2f){a.y, bq.y};
        Hr[k] = (v2f){0.0f, 0.0f};
        Hi[k] = (v2f){0.0f, 0.0f};
    }
    const float* xp = x + (size_t)(c * CHUNK) * LBD + b * DM + d;
#pragma unroll
    for (int l0 = 0; l0 < CHUNK; l0 += 4) {
        float xv0 = xp[(size_t)(l0 + 0) * LBD];
        float xv1 = xp[(size_t)(l0 + 1) * LBD];
        float xv2 = xp[(size_t)(l0 + 2) * LBD];
        float xv3 = xp[(size_t)(l0 + 3) * LBD];
#define P1STEP(XV)                                                            \
        {                                                                     \
            v2f X = {XV, XV};                                                 \
            _Pragma("unroll")                                                 \
            for (int k = 0; k < NV; ++k) {                                    \
                v2f nr = __builtin_elementwise_fma(Qr[k], Hr[k],              \
                          __builtin_elementwise_fma(-Qi[k], Hi[k], X));       \
                v2f ni = __builtin_elementwise_fma(Qr[k], Hi[k],              \
                                                   Qi[k] * Hr[k]);            \
                Hr[k] = nr; Hi[k] = ni;                                       \
            }                                                                 \
        }
        P1STEP(xv0) P1STEP(xv1) P1STEP(xv2) P1STEP(xv3)
#undef P1STEP
    }
    float2* sp = S + ((size_t)bc * NS + nb) * DM + d;
#pragma unroll
    for (int k = 0; k < NV; ++k) {
        sp[(size_t)(2 * k) * DM]     = make_float2(Hr[k].x, Hi[k].x);
        sp[(size_t)(2 * k + 1) * DM] = make_float2(Hr[k].y, Hi[k].y);
    }
}

// ---------------------------------------------------------------- pass 2
// Inter-chunk scan in place, 8-deep static prefetch pipeline.
__global__ __launch_bounds__(256)
void s4d_pass2(const float2* __restrict__ qbuf,
               float2* __restrict__ S) {
    int tid = blockIdx.x * 256 + threadIdx.x;        // BSZ*DM*NS threads
    int d = tid & (DM - 1);
    int n = (tid >> 10) & (NS - 1);
    int b = tid >> 14;
    float2 qv = qbuf[n * DM + d];
    float qr = qv.x, qi = qv.y;
#pragma unroll
    for (int i = 0; i < LOG2_CHUNK; ++i) {           // q^CHUNK
        float nr = qr * qr - qi * qi;
        float ni = 2.0f * qr * qi;
        qr = nr; qi = ni;
    }
    size_t base = ((size_t)b * NCHUNK * NS + n) * DM + d;
    const size_t cs = (size_t)NS * DM;               // stride between chunks
    float hr = 0.0f, hi = 0.0f;
    float2 s0 = S[base + 0 * cs], s1 = S[base + 1 * cs],
           s2 = S[base + 2 * cs], s3 = S[base + 3 * cs],
           s4 = S[base + 4 * cs], s5 = S[base + 5 * cs],
           s6 = S[base + 6 * cs], s7 = S[base + 7 * cs];
#pragma unroll
    for (int c0 = 0; c0 < NCHUNK; c0 += 8) {
        float2 t0, t1, t2, t3, t4, t5, t6, t7;
        if (c0 + 8 < NCHUNK) {                       // static after unroll
            size_t nb2 = base + (size_t)(c0 + 8) * cs;
            t0 = S[nb2 + 0 * cs]; t1 = S[nb2 + 1 * cs];
            t2 = S[nb2 + 2 * cs]; t3 = S[nb2 + 3 * cs];
            t4 = S[nb2 + 4 * cs]; t5 = S[nb2 + 5 * cs];
            t6 = S[nb2 + 6 * cs]; t7 = S[nb2 + 7 * cs];
        }
#define STEP(J, SB)                                                      \
        {                                                                \
            S[base + (size_t)(c0 + J) * cs] = make_float2(hr, hi);       \
            float nr = fmaf(qr, hr, fmaf(-qi, hi, SB.x));                \
            float ni = fmaf(qr, hi, fmaf(qi, hr, SB.y));                 \
            hr = nr; hi = ni;                                            \
        }
        STEP(0, s0) STEP(1, s1) STEP(2, s2) STEP(3, s3)
        STEP(4, s4) STEP(5, s5) STEP(6, s6) STEP(7, s7)
#undef STEP
        if (c0 + 8 < NCHUNK) {
            s0 = t0; s1 = t1; s2 = t2; s3 = t3;
            s4 = t4; s5 = t5; s6 = t6; s7 = t7;
        }
    }
}

// ---------------------------------------------------------------- pass 3
// 2 threads per (b,c,d), 8 states each (4 v2f pairs), replay + fused epilogue.
__attribute__((amdgpu_waves_per_eu(4, 4)))
__global__ __launch_bounds__(256)
void s4d_pass3(const float* __restrict__ x,
               const float* __restrict__ Dp,
               const float2* __restrict__ qbuf,
               const float2* __restrict__ pbuf,
               const float2* __restrict__ S,
               float* __restrict__ out) {
    int tid  = blockIdx.x * 256 + threadIdx.x;
    int lane = tid & 63;
    int dlo  = lane & 31;
    int half = lane >> 5;
    int u    = tid >> 6;
    int dhi  = u & 31;
    int bc   = u >> 5;
    int c    = bc & (NCHUNK - 1);
    int d    = dhi * 32 + dlo;
    int b    = bc >> LOG2_CHUNK;
    int nb   = half * NSH;

    v2f Qr[NV], Qi[NV], Pr[NV], Pi[NV], Hr[NV], Hi[NV];
#pragma unroll
    for (int k = 0; k < NV; ++k) {
        float2 a0 = qbuf[(nb + 2 * k) * DM + d];
        float2 a1 = qbuf[(nb + 2 * k + 1) * DM + d];
        float2 w0 = pbuf[(nb + 2 * k) * DM + d];
        float2 w1 = pbuf[(nb + 2 * k + 1) * DM + d];
        Qr[k] = (v2f){a0.x, a1.x};
        Qi[k] = (v2f){a0.y, a1.y};
        Pr[k] = (v2f){w0.x, w1.x};
        Pi[k] = (v2f){w0.y, w1.y};
    }
    const float2* sp = S + ((size_t)bc * NS + nb) * DM + d;
#pragma unroll
    for (int k = 0; k < NV; ++k) {
        float2 s0 = sp[(size_t)(2 * k) * DM];
        float2 s1 = sp[(size_t)(2 * k + 1) * DM];
        Hr[k] = (v2f){s0.x, s1.x};
        Hi[k] = (v2f){s0.y, s1.y};
    }
    float dpar = Dp[d];
    const float* xp = x + (size_t)(c * CHUNK) * LBD + b * DM + d;
    float* op = out + (size_t)(c * CHUNK) * LBD + b * DM + d;
#pragma unroll
    for (int l0 = 0; l0 < CHUNK; l0 += 4) {
        float xv0 = xp[(size_t)(l0 + 0) * LBD];
        float xv1 = xp[(size_t)(l0 + 1) * LBD];
        float xv2 = xp[(size_t)(l0 + 2) * LBD];
        float xv3 = xp[(size_t)(l0 + 3) * LBD];
        float acc0, acc1, acc2, acc3;
#define P3STEP(XV, ACC)                                                       \
        {                                                                     \
            v2f X = {XV, XV};                                                 \
            v2f A = {0.0f, 0.0f};                                             \
            _Pragma("unroll")                                                 \
            for (int k = 0; k < NV; ++k) {                                    \
                v2f nr = __builtin_elementwise_fma(Qr[k], Hr[k],              \
                          __builtin_elementwise_fma(-Qi[k], Hi[k], X));       \
                v2f ni = __builtin_elementwise_fma(Qr[k], Hi[k],              \
                                                   Qi[k] * Hr[k]);            \
                Hr[k] = nr; Hi[k] = ni;                                       \
                A = __builtin_elementwise_fma(Pr[k], nr,                      \
                     __builtin_elementwise_fma(-Pi[k], ni, A));               \
            }                                                                 \
            ACC = A.x + A.y;                                                  \
        }
        P3STEP(xv0, acc0) P3STEP(xv1, acc1) P3STEP(xv2, acc2) P3STEP(xv3, acc3)
#undef P3STEP
        acc0 += __shfl_xor(acc0, 32, 64);            // combine n-halves
        acc1 += __shfl_xor(acc1, 32, 64);
        acc2 += __shfl_xor(acc2, 32, 64);
        acc3 += __shfl_xor(acc3, 32, 64);
        float z0 = fmaf(xv0, dpar, acc0);
        float z1 = fmaf(xv1, dpar, acc1);
        float z2 = fmaf(xv2, dpar, acc2);
        float z3 = fmaf(xv3, dpar, acc3);
        float r0 = z0 * __builtin_amdgcn_rcpf(1.0f + __expf(-z0));
        float r1 = z1 * __builtin_amdgcn_rcpf(1.0f + __expf(-z1));
        float r2 = z2 * __builtin_amdgcn_rcpf(1.0f + __expf(-z2));
        float r3 = z3 * __builtin_amdgcn_rcpf(1.0f + __expf(-z3));
        if (half == 0) {
            op[(size_t)(l0 + 0) * LBD] = r0;
            op[(size_t)(l0 + 1) * LBD] = r1;
            op[(size_t)(l0 + 2) * LBD] = r2;
            op[(size_t)(l0 + 3) * LBD] = r3;
        }
    }
}

// ---------------------------------------------------------------- launch
extern "C" void kernel_launch(void* const* d_in, const int* in_sizes, int n_in,
                              void* d_out, int out_size, void* d_ws, size_t ws_size,
                              hipStream_t stream) {
    const float* x          = (const float*)d_in[0];
    const float* log_dt     = (const float*)d_in[1];
    const float* log_A_real = (const float*)d_in[2];
    const float* A_imag     = (const float*)d_in[3];
    const float* Bp         = (const float*)d_in[4];
    const float* Cp         = (const float*)d_in[5];
    const float* Dp         = (const float*)d_in[6];
    float* out = (float*)d_out;

    float2* qbuf = (float2*)d_ws;
    float2* pbuf = qbuf + NS * DM;
    float2* S    = pbuf + NS * DM;

    hipLaunchKernelGGL(s4d_params, dim3((NS * DM) / 256), dim3(256), 0, stream,
                       log_dt, log_A_real, A_imag, Bp, Cp, qbuf, pbuf);
    hipLaunchKernelGGL(s4d_pass1, dim3((2 * BSZ * NCHUNK * DM) / 256), dim3(256), 0, stream,
                       x, qbuf, S);
    hipLaunchKernelGGL(s4d_pass2, dim3((BSZ * DM * NS) / 256), dim3(256), 0, stream,
                       qbuf, S);
    hipLaunchKernelGGL(s4d_pass3, dim3((2 * BSZ * NCHUNK * DM) / 256), dim3(256), 0, stream,
                       x, Dp, qbuf, pbuf, S, out);
}

// Round 8
// 193.880 us; speedup vs baseline: 1.0078x; 1.0078x over previous
//
#include <hip/hip_runtime.h>
#include <math.h>

// S4D via chunked linear-scan recurrence. x (L,B,D) f32, out (L,B,D) f32.
// R8: software-pipelined x loads (2x8 batches), hierarchical pass2, 
//     pass1 at 8 waves/EU, epilogue on half 0 only.
#define L_SEQ  4096
#define BSZ    4
#define DM     1024
#define NS     16
#define NSH    8                  // states per thread (n-split across wave halves)
#define NV     (NSH / 2)          // v2f vectors per array (2 states each)
#define NCHUNK 64
#define CHUNK  (L_SEQ / NCHUNK)   // 64
#define LOG2_CHUNK 6
#define GRP    8                  // chunks per scan group
#define NG     (NCHUNK / GRP)     // 8 groups
#define SCALE  0.25f
#define LBD    (BSZ * DM)         // 4096, x stride per l

typedef float v2f __attribute__((ext_vector_type(2)));

// ws layout:
//   qbuf float2[NS*DM]            128 KiB   (indexed n*DM + d)
//   pbuf float2[NS*DM]            128 KiB
//   S    float2[BSZ*NCHUNK*NS*DM] 33.5 MiB  (indexed ((bc*NS)+n)*DM + d)
//   GT   float2[BSZ*NG*NS*DM]     4 MiB     (indexed (((b*NG+g)*NS)+n)*DM + d)

// ---------------------------------------------------------------- params
__global__ void s4d_params(const float* __restrict__ log_dt,
                           const float* __restrict__ log_A_real,
                           const float* __restrict__ A_imag,
                           const float* __restrict__ Bp,
                           const float* __restrict__ Cp,
                           float2* __restrict__ qbuf,
                           float2* __restrict__ pbuf) {
    int t = blockIdx.x * blockDim.x + threadIdx.x;   // t = n*DM + d
    if (t >= NS * DM) return;
    int n = t >> 10, d = t & (DM - 1);
    int i = d * NS + n;                              // input layout (D,N)
    float dt = expf(log_dt[d]);
    float Ar = -expf(log_A_real[i]);
    float Ai = A_imag[i];
    float ar = 0.5f * Ar * dt, ai = 0.5f * Ai * dt;  // dtA/2
    float den_r = 1.0f - ar, den_i = -ai;            // 1 - dtA/2
    float num_r = 1.0f + ar, num_i = ai;             // 1 + dtA/2
    float inv = 1.0f / (den_r * den_r + den_i * den_i);
    float qr = (num_r * den_r + num_i * den_i) * inv;
    float qi = (num_i * den_r - num_r * den_i) * inv;
    float B0 = Bp[2 * i], B1 = Bp[2 * i + 1];
    float C0 = Cp[2 * i], C1 = Cp[2 * i + 1];
    float ccr = B0 * C0 - B1 * C1;
    float cci = B0 * C1 + B1 * C0;
    float s = dt * inv * SCALE;
    float pr = (ccr * den_r + cci * den_i) * s;
    float pi = (cci * den_r - ccr * den_i) * s;
    qbuf[t] = make_float2(qr, qi);
    pbuf[t] = make_float2(pr, pi);
}

// ---------------------------------------------------------------- pass 1
// 2 threads per (b,c,d), 8 states each (4 v2f); pipelined 8-deep x loads.
__attribute__((amdgpu_waves_per_eu(6, 8)))
__global__ __launch_bounds__(256)
void s4d_pass1(const float* __restrict__ x,
               const float2* __restrict__ qbuf,
               float2* __restrict__ S) {
    int tid  = blockIdx.x * 256 + threadIdx.x;       // 2*BSZ*NCHUNK*DM threads
    int lane = tid & 63;
    int dlo  = lane & 31;
    int half = lane >> 5;
    int u    = tid >> 6;
    int dhi  = u & 31;
    int bc   = u >> 5;                               // b*NCHUNK + c
    int c    = bc & (NCHUNK - 1);
    int d    = dhi * 32 + dlo;
    int b    = bc >> LOG2_CHUNK;
    int nb   = half * NSH;

    v2f Qr[NV], Qi[NV], Hr[NV], Hi[NV];
#pragma unroll
    for (int k = 0; k < NV; ++k) {
        float2 a = qbuf[(nb + 2 * k) * DM + d];
        float2 bq = qbuf[(nb + 2 * k + 1) * DM + d];
        Qr[k] = (v2f){a.x, bq.x};
        Qi[k] = (v2f){a.y, bq.y};
        Hr[k] = (v2f){0.0f, 0.0f};
        Hi[k] = (v2f){0.0f, 0.0f};
    }
    const float* xp = x + (size_t)(c * CHUNK) * LBD + b * DM + d;
    float xa[8], xb[8];
#define LOADX(ARR, L0)                                                        \
    { _Pragma("unroll")                                                       \
      for (int j = 0; j < 8; ++j) ARR[j] = xp[(size_t)((L0) + j) * LBD]; }
#define STEP1(XV)                                                             \
    { v2f X = {XV, XV};                                                       \
      _Pragma("unroll")                                                       \
      for (int k = 0; k < NV; ++k) {                                          \
          v2f nr = __builtin_elementwise_fma(Qr[k], Hr[k],                    \
                    __builtin_elementwise_fma(-Qi[k], Hi[k], X));             \
          v2f ni = __builtin_elementwise_fma(Qr[k], Hi[k], Qi[k] * Hr[k]);    \
          Hr[k] = nr; Hi[k] = ni;                                             \
      } }
#define COMP1(ARR)                                                            \
    { _Pragma("unroll")                                                       \
      for (int j = 0; j < 8; ++j) STEP1(ARR[j]) }
    LOADX(xa, 0)  LOADX(xb, 8)
    COMP1(xa)     LOADX(xa, 16)
    COMP1(xb)     LOADX(xb, 24)
    COMP1(xa)     LOADX(xa, 32)
    COMP1(xb)     LOADX(xb, 40)
    COMP1(xa)     LOADX(xa, 48)
    COMP1(xb)     LOADX(xb, 56)
    COMP1(xa)
    COMP1(xb)
#undef COMP1
#undef STEP1
    float2* sp = S + ((size_t)bc * NS + nb) * DM + d;
#pragma unroll
    for (int k = 0; k < NV; ++k) {
        sp[(size_t)(2 * k) * DM]     = make_float2(Hr[k].x, Hi[k].x);
        sp[(size_t)(2 * k + 1) * DM] = make_float2(Hr[k].y, Hi[k].y);
    }
}

// ---------------------------------------------------------------- pass 2a
// In-place scan WITHIN groups of 8 chunks; one thread per (b,d,n,g).
// 8x the parallelism of the old pass2 (8 waves/SIMD). Emits group totals.
__global__ __launch_bounds__(256)
void s4d_pass2a(const float2* __restrict__ qbuf,
                float2* __restrict__ S,
                float2* __restrict__ GT) {
    int tid = blockIdx.x * 256 + threadIdx.x;        // BSZ*NG*NS*DM threads
    int d = tid & (DM - 1);
    int n = (tid >> 10) & (NS - 1);
    int g = (tid >> 14) & (NG - 1);
    int b = tid >> 17;
    float2 qv = qbuf[n * DM + d];
    float qr = qv.x, qi = qv.y;
#pragma unroll
    for (int i = 0; i < LOG2_CHUNK; ++i) {           // qL = q^CHUNK
        float nr = qr * qr - qi * qi;
        float ni = 2.0f * qr * qi;
        qr = nr; qi = ni;
    }
    size_t base = ((size_t)(b * NCHUNK + g * GRP) * NS + n) * DM + d;
    const size_t cs = (size_t)NS * DM;
    float2 s0 = S[base + 0 * cs], s1 = S[base + 1 * cs],
           s2 = S[base + 2 * cs], s3 = S[base + 3 * cs],
           s4 = S[base + 4 * cs], s5 = S[base + 5 * cs],
           s6 = S[base + 6 * cs], s7 = S[base + 7 * cs];
    float hr = 0.0f, hi = 0.0f;
#define ST2(J, SB)                                                       \
    {                                                                    \
        S[base + (size_t)(J) * cs] = make_float2(hr, hi);                \
        float nr = fmaf(qr, hr, fmaf(-qi, hi, SB.x));                    \
        float ni = fmaf(qr, hi, fmaf(qi, hr, SB.y));                     \
        hr = nr; hi = ni;                                                \
    }
    ST2(0, s0) ST2(1, s1) ST2(2, s2) ST2(3, s3)
    ST2(4, s4) ST2(5, s5) ST2(6, s6) ST2(7, s7)
#undef ST2
    GT[((size_t)(b * NG + g) * NS + n) * DM + d] = make_float2(hr, hi);
}

// ---------------------------------------------------------------- pass 2b
// Scan of the 8 group totals per (b,d,n), in place: GT[g] <- incoming.
__global__ __launch_bounds__(256)
void s4d_pass2b(const float2* __restrict__ qbuf,
                float2* __restrict__ GT) {
    int tid = blockIdx.x * 256 + threadIdx.x;        // BSZ*NS*DM threads
    int d = tid & (DM - 1);
    int n = (tid >> 10) & (NS - 1);
    int b = tid >> 14;
    float2 qv = qbuf[n * DM + d];
    float qr = qv.x, qi = qv.y;
#pragma unroll
    for (int i = 0; i < LOG2_CHUNK + 3; ++i) {       // q^(CHUNK*GRP) = q^512
        float nr = qr * qr - qi * qi;
        float ni = 2.0f * qr * qi;
        qr = nr; qi = ni;
    }
    size_t gbase = ((size_t)(b * NG) * NS + n) * DM + d;
    const size_t gs = (size_t)NS * DM;
    float2 t0 = GT[gbase + 0 * gs], t1 = GT[gbase + 1 * gs],
           t2 = GT[gbase + 2 * gs], t3 = GT[gbase + 3 * gs],
           t4 = GT[gbase + 4 * gs], t5 = GT[gbase + 5 * gs],
           t6 = GT[gbase + 6 * gs], t7 = GT[gbase + 7 * gs];
    float hr = 0.0f, hi = 0.0f;
#define STB(J, SB)                                                       \
    {                                                                    \
        GT[gbase + (size_t)(J) * gs] = make_float2(hr, hi);              \
        float nr = fmaf(qr, hr, fmaf(-qi, hi, SB.x));                    \
        float ni = fmaf(qr, hi, fmaf(qi, hr, SB.y));                     \
        hr = nr; hi = ni;                                                \
    }
    STB(0, t0) STB(1, t1) STB(2, t2) STB(3, t3)
    STB(4, t4) STB(5, t5) STB(6, t6) STB(7, t7)
#undef STB
}

// ---------------------------------------------------------------- pass 3
// 2 threads per (b,c,d), 8 states each; incoming = S_within + qL^(c&7)*GT[g];
// pipelined 8-deep x loads; epilogue + store on half 0 only.
__attribute__((amdgpu_waves_per_eu(4, 4)))
__global__ __launch_bounds__(256)
void s4d_pass3(const float* __restrict__ x,
               const float* __restrict__ Dp,
               const float2* __restrict__ qbuf,
               const float2* __restrict__ pbuf,
               const float2* __restrict__ S,
               const float2* __restrict__ GT,
               float* __restrict__ out) {
    int tid  = blockIdx.x * 256 + threadIdx.x;
    int lane = tid & 63;
    int dlo  = lane & 31;
    int half = lane >> 5;
    int u    = tid >> 6;
    int dhi  = u & 31;
    int bc   = u >> 5;
    int c    = bc & (NCHUNK - 1);
    int d    = dhi * 32 + dlo;
    int b    = bc >> LOG2_CHUNK;
    int nb   = half * NSH;
    int g    = c >> 3;
    int jj   = c & 7;                                // wave-uniform

    v2f Qr[NV], Qi[NV], Pr[NV], Pi[NV], Hr[NV], Hi[NV];
#pragma unroll
    for (int k = 0; k < NV; ++k) {
        float2 a0 = qbuf[(nb + 2 * k) * DM + d];
        float2 a1 = qbuf[(nb + 2 * k + 1) * DM + d];
        float2 w0 = pbuf[(nb + 2 * k) * DM + d];
        float2 w1 = pbuf[(nb + 2 * k + 1) * DM + d];
        Qr[k] = (v2f){a0.x, a1.x};
        Qi[k] = (v2f){a0.y, a1.y};
        Pr[k] = (v2f){w0.x, w1.x};
        Pi[k] = (v2f){w0.y, w1.y};
    }
    const float2* sp = S + ((size_t)bc * NS + nb) * DM + d;
    const float2* gp = GT + ((size_t)(b * NG + g) * NS + nb) * DM + d;
#pragma unroll
    for (int k = 0; k < NV; ++k) {
        float2 s0 = sp[(size_t)(2 * k) * DM];
        float2 s1 = sp[(size_t)(2 * k + 1) * DM];
        float2 g0 = gp[(size_t)(2 * k) * DM];
        float2 g1 = gp[(size_t)(2 * k + 1) * DM];
        v2f Gr = (v2f){g0.x, g1.x};
        v2f Gi = (v2f){g0.y, g1.y};
        // w = qL^jj, qL = q^CHUNK (6 squarings)
        v2f ar = Qr[k], ai = Qi[k];
#pragma unroll
        for (int i = 0; i < LOG2_CHUNK; ++i) {
            v2f nr = __builtin_elementwise_fma(-ai, ai, ar * ar);
            v2f ni = (ar + ar) * ai;
            ar = nr; ai = ni;
        }
        v2f wr = (v2f){1.0f, 1.0f}, wi = (v2f){0.0f, 0.0f};
        if (jj & 1) {
            v2f tr = __builtin_elementwise_fma(-wi, ai, wr * ar);
            v2f ti = __builtin_elementwise_fma(wi, ar, wr * ai);
            wr = tr; wi = ti;
        }
        { v2f nr = __builtin_elementwise_fma(-ai, ai, ar * ar);
          v2f ni = (ar + ar) * ai; ar = nr; ai = ni; }      // qL^2
        if (jj & 2) {
            v2f tr = __builtin_elementwise_fma(-wi, ai, wr * ar);
            v2f ti = __builtin_elementwise_fma(wi, ar, wr * ai);
            wr = tr; wi = ti;
        }
        { v2f nr = __builtin_elementwise_fma(-ai, ai, ar * ar);
          v2f ni = (ar + ar) * ai; ar = nr; ai = ni; }      // qL^4
        if (jj & 4) {
            v2f tr = __builtin_elementwise_fma(-wi, ai, wr * ar);
            v2f ti = __builtin_elementwise_fma(wi, ar, wr * ai);
            wr = tr; wi = ti;
        }
        // incoming = S_within + w*G
        v2f sr = (v2f){s0.x, s1.x};
        v2f si = (v2f){s0.y, s1.y};
        Hr[k] = __builtin_elementwise_fma(wr, Gr,
                 __builtin_elementwise_fma(-wi, Gi, sr));
        Hi[k] = __builtin_elementwise_fma(wr, Gi,
                 __builtin_elementwise_fma(wi, Gr, si));
    }
    float dpar = Dp[d];
    const float* xp = x + (size_t)(c * CHUNK) * LBD + b * DM + d;
    float* op = out + (size_t)(c * CHUNK) * LBD + b * DM + d;
    float xa[8], xb[8];
#define COMP3(ARR, L0)                                                        \
    { float av[8];                                                            \
      _Pragma("unroll")                                                       \
      for (int j = 0; j < 8; ++j) {                                           \
          v2f X = {ARR[j], ARR[j]};                                           \
          v2f A = {0.0f, 0.0f};                                               \
          _Pragma("unroll")                                                   \
          for (int k = 0; k < NV; ++k) {                                      \
              v2f nr = __builtin_elementwise_fma(Qr[k], Hr[k],                \
                        __builtin_elementwise_fma(-Qi[k], Hi[k], X));         \
              v2f ni = __builtin_elementwise_fma(Qr[k], Hi[k],                \
                                                 Qi[k] * Hr[k]);              \
              Hr[k] = nr; Hi[k] = ni;                                         \
              A = __builtin_elementwise_fma(Pr[k], nr,                        \
                   __builtin_elementwise_fma(-Pi[k], ni, A));                 \
          }                                                                   \
          av[j] = A.x + A.y;                                                  \
      }                                                                       \
      _Pragma("unroll")                                                       \
      for (int j = 0; j < 8; ++j) av[j] += __shfl_xor(av[j], 32, 64);         \
      if (half == 0) {                                                        \
          _Pragma("unroll")                                                   \
          for (int j = 0; j < 8; ++j) {                                       \
              float z = fmaf(ARR[j], dpar, av[j]);                            \
              float sg = __builtin_amdgcn_rcpf(1.0f + __expf(-z));            \
              op[(size_t)((L0) + j) * LBD] = z * sg;                          \
          }                                                                   \
      } }
    LOADX(xa, 0)  LOADX(xb, 8)
    COMP3(xa, 0)  LOADX(xa, 16)
    COMP3(xb, 8)  LOADX(xb, 24)
    COMP3(xa, 16) LOADX(xa, 32)
    COMP3(xb, 24) LOADX(xb, 40)
    COMP3(xa, 32) LOADX(xa, 48)
    COMP3(xb, 40) LOADX(xb, 56)
    COMP3(xa, 48)
    COMP3(xb, 56)
#undef COMP3
#undef LOADX
}

// ---------------------------------------------------------------- launch
extern "C" void kernel_launch(void* const* d_in, const int* in_sizes, int n_in,
                              void* d_out, int out_size, void* d_ws, size_t ws_size,
                              hipStream_t stream) {
    const float* x          = (const float*)d_in[0];
    const float* log_dt     = (const float*)d_in[1];
    const float* log_A_real = (const float*)d_in[2];
    const float* A_imag     = (const float*)d_in[3];
    const float* Bp         = (const float*)d_in[4];
    const float* Cp         = (const float*)d_in[5];
    const float* Dp         = (const float*)d_in[6];
    float* out = (float*)d_out;

    float2* qbuf = (float2*)d_ws;
    float2* pbuf = qbuf + NS * DM;
    float2* S    = pbuf + NS * DM;
    float2* GT   = S + (size_t)BSZ * NCHUNK * NS * DM;

    hipLaunchKernelGGL(s4d_params, dim3((NS * DM) / 256), dim3(256), 0, stream,
                       log_dt, log_A_real, A_imag, Bp, Cp, qbuf, pbuf);
    hipLaunchKernelGGL(s4d_pass1, dim3((2 * BSZ * NCHUNK * DM) / 256), dim3(256), 0, stream,
                       x, qbuf, S);
    hipLaunchKernelGGL(s4d_pass2a, dim3((BSZ * NG * NS * DM) / 256), dim3(256), 0, stream,
                       qbuf, S, GT);
    hipLaunchKernelGGL(s4d_pass2b, dim3((BSZ * NS * DM) / 256), dim3(256), 0, stream,
                       qbuf, GT);
    hipLaunchKernelGGL(s4d_pass3, dim3((2 * BSZ * NCHUNK * DM) / 256), dim3(256), 0, stream,
                       x, Dp, qbuf, pbuf, S, GT, out);
}